// Round 10
// baseline (468.057 us; speedup 1.0000x reference)
//
#include <hip/hip_runtime.h>
#include <math.h>

#define DIMK 2048
#define NEMB 16384
#define NB 256
#define NR2 1536          // 256*6 neighbor rows
#define INV_BETA 20.0f
#define NEG_INF (-3.0e38f)

typedef short short8 __attribute__((ext_vector_type(8)));
typedef float f32x4 __attribute__((ext_vector_type(4)));

__device__ __forceinline__ unsigned short f2bf(float f) {
  unsigned u = __float_as_uint(f);
  u += 0x7fffu + ((u >> 16) & 1u);
  return (unsigned short)(u >> 16);
}

// top-6 insert with (value desc, index asc) tie-break — matches jax top_k order
__device__ __forceinline__ void ins6i(float x, int xi, float v[6], int vi[6]) {
  if (x > v[5] || (x == v[5] && xi < vi[5])) {
    v[5] = x; vi[5] = xi;
#pragma unroll
    for (int j = 5; j > 0; j--) {
      if (v[j] > v[j - 1] || (v[j] == v[j - 1] && vi[j] < vi[j - 1])) {
        float tv = v[j]; v[j] = v[j - 1]; v[j - 1] = tv;
        int ti = vi[j]; vi[j] = vi[j - 1]; vi[j - 1] = ti;
      }
    }
  }
}

__global__ __launch_bounds__(256) void cvt_kernel(const float* __restrict__ src,
                                                  unsigned short* __restrict__ dst, int n4) {
  int i = blockIdx.x * 256 + threadIdx.x;
  if (i < n4) {
    float4 f = ((const float4*)src)[i];
    ushort4 o;
    o.x = f2bf(f.x); o.y = f2bf(f.y); o.z = f2bf(f.z); o.w = f2bf(f.w);
    ((ushort4*)dst)[i] = o;
  }
}

// ---------------- K-split reg-staged GEMM (R9's verified 2-deep loop, NK->NKC) ----------
// Wall-time is latency-bound at ~1.4 us/K-iter/block (invariant over 4 schedules), so
// stages are cut by splitting K across blocks (blockIdx.z) and materializing fp32
// partial sums; threshold counting moves to cheap streaming kernels.
//
// MODE 0: partial logits. NKC=32, grid (128,4,2). out: lpart[z][256][16384] (*20).
// MODE 1: sims phase A (cols 0..2048). NKC=16, grid (16,12,4). out simsA[z][1536][2048].
// MODE 2: sims phase B (cols 2048..16384), survivor rows only (full 1536 coverage,
//         blocks past nsurv exit). NKC=32, grid (112,12,2). out simsB[z][1536][14336].
template <int MODE>
__global__ __launch_bounds__(256, 3) void gemm_ks(
    const unsigned short* __restrict__ Abase, const unsigned short* __restrict__ Bbase,
    const int* __restrict__ nidx, float* __restrict__ outP,
    const int* __restrict__ surv, const int* __restrict__ nsurvp) {
  constexpr int MTILE = (MODE == 0) ? 64 : 128;
  constexpr int MI = 4;
  constexpr int NI = (MODE == 0) ? 2 : 4;
  constexpr int NSUB_A = MTILE / 16;   // 4 or 8
  constexpr int NSUB = NSUB_A + 8;     // 12 or 16
  constexpr int NA = NSUB / 4;
  constexpr int NKC = (MODE == 1) ? 16 : 32;      // K-iters per block (chunked)
  constexpr int OSTRIDE = (MODE == 0) ? 16384 : ((MODE == 1) ? 2048 : 14336);
  constexpr size_t PLANE = (size_t)((MODE == 0) ? 256 : 1536) * OSTRIDE;

  __shared__ unsigned short st[2][NSUB * 512];
  __shared__ int rowIdxSh[128];
  int t = threadIdx.x;
  int lane = t & 63, wave = t >> 6;
  int quad = lane >> 4, l16 = lane & 15;
  int wr = (MODE == 0) ? 0 : (wave >> 1);
  int wc = (MODE == 0) ? wave : (wave & 1);
  int bn = blockIdx.x, bm = blockIdx.y, kz = blockIdx.z;

  if constexpr (MODE == 2) {
    int ns = nsurvp[0];
    if (bm * 128 >= ns) return;        // uniform, before any barrier
    if (t < 128) {
      int idx = bm * 128 + t;
      int r = surv[(idx < ns) ? idx : (bm * 128)];   // pad dup (ignored by countB)
      rowIdxSh[t] = nidx[r];
    }
    __syncthreads();
  }
  if constexpr (MODE == 1) {
    if (t < 128) rowIdxSh[t] = nidx[bm * 128 + t];
    __syncthreads();
  }

  int colbase = (MODE == 2) ? ((bn + 16) * 128) : (bn * 128);
  int kbase = kz * (NKC * 32);   // shorts

  const unsigned short* agp[NA];
  int soff[NA];
  {
    int seg = lane >> 4;
#pragma unroll
    for (int a = 0; a < NA; a++) {
      int s = wave + a * 4;
      size_t grow;
      const unsigned short* basep;
      if (s < NSUB_A) {
        int r = s * 16 + l16;
        grow = (MODE == 0) ? (size_t)(bm * MTILE + r) : (size_t)rowIdxSh[r];
        basep = Abase;
      } else {
        grow = (size_t)(colbase + (s - NSUB_A) * 16 + l16);
        basep = Bbase;
      }
      agp[a] = basep + grow * DIMK + kbase + seg * 8;
      soff[a] = s * 512;
    }
  }

  f32x4 acc[MI][NI];
#pragma unroll
  for (int mi = 0; mi < MI; mi++)
#pragma unroll
    for (int ni = 0; ni < NI; ni++) acc[mi][ni] = (f32x4)0.0f;

  int lo = lane * 8;

  short8 rA[NA], rB2[NA];
  auto LOADT = [&](short8* R, int kk) {
#pragma unroll
    for (int a = 0; a < NA; a++) R[a] = *(const short8*)(agp[a] + kk * 32);
  };
  auto WRITET = [&](const short8* R, int b) {
#pragma unroll
    for (int a = 0; a < NA; a++) *(short8*)&st[b][soff[a] + lo] = R[a];
  };
  auto COMPUTE = [&](int b) {
    const unsigned short* hb = &st[b][0];
    short8 af[MI], bfv[NI];
#pragma unroll
    for (int mi = 0; mi < MI; mi++)
      af[mi] = *(const short8*)&hb[(wr * MI + mi) * 512 + lo];
#pragma unroll
    for (int ni = 0; ni < NI; ni++)
      bfv[ni] = *(const short8*)&hb[(NSUB_A + wc * NI + ni) * 512 + lo];
#pragma unroll
    for (int mi = 0; mi < MI; mi++)
#pragma unroll
      for (int ni = 0; ni < NI; ni++)
        acc[mi][ni] =
            __builtin_amdgcn_mfma_f32_16x16x32_bf16(af[mi], bfv[ni], acc[mi][ni], 0, 0, 0);
  };

  LOADT(rA, 0);
  LOADT(rB2, 1);
  WRITET(rA, 0);
  __syncthreads();
  for (int k = 0; k < NKC; k += 2) {
    if (k + 2 < NKC) LOADT(rA, k + 2);
    COMPUTE(0);
    WRITET(rB2, 1);
    __syncthreads();
    if (k + 3 < NKC) LOADT(rB2, k + 3);
    COMPUTE(1);
    if (k + 2 < NKC) WRITET(rA, 0);
    __syncthreads();
  }

  float* op = outP + (size_t)kz * PLANE;
  if constexpr (MODE == 0) {
#pragma unroll
    for (int mi = 0; mi < MI; mi++) {
      int row = bm * MTILE + mi * 16 + quad * 4;
#pragma unroll
      for (int ni = 0; ni < NI; ni++) {
        int col = bn * 128 + wave * 32 + ni * 16 + l16;
#pragma unroll
        for (int rr = 0; rr < 4; rr++)
          op[(size_t)(row + rr) * OSTRIDE + col] = acc[mi][ni][rr] * INV_BETA;
      }
    }
  } else {
#pragma unroll
    for (int mi = 0; mi < MI; mi++) {
#pragma unroll
      for (int ni = 0; ni < NI; ni++) {
        int col = bn * 128 + wc * 64 + ni * 16 + l16;
#pragma unroll
        for (int rr = 0; rr < 4; rr++) {
          int row = bm * 128 + wr * 64 + mi * 16 + quad * 4 + rr;
          op[(size_t)row * OSTRIDE + col] = acc[mi][ni][rr];
        }
      }
    }
  }
}

// count phase A: cnt[row] += #(sum of 4 partials > sa[row]) over cols 0..2048
__global__ __launch_bounds__(256) void countA_kernel(const float* __restrict__ simsA,
                                                     const float* __restrict__ sa,
                                                     int* __restrict__ cnt) {
  int t = threadIdx.x, lane = t & 63;
  constexpr size_t PL = (size_t)1536 * 2048;
  for (int it = blockIdx.x; it < 1536 * 8; it += 256) {
    int row = it >> 3, cx = it & 7;
    size_t o = (size_t)row * 2048 + cx * 256 + t;
    float s = simsA[o] + simsA[o + PL] + simsA[o + 2 * PL] + simsA[o + 3 * PL];
    int c = (s > sa[row]) ? 1 : 0;
#pragma unroll
    for (int off = 32; off > 0; off >>= 1) c += __shfl_down(c, off, 64);
    if (lane == 0 && c > 0) atomicAdd(&cnt[row], c);
  }
}

// count phase B: survivors only, cols 2048..16384 (buffer cols 0..14336)
__global__ __launch_bounds__(256) void countB_kernel(const float* __restrict__ simsB,
                                                     const float* __restrict__ sa,
                                                     const int* __restrict__ surv,
                                                     const int* __restrict__ nsurvp,
                                                     int* __restrict__ cnt) {
  int t = threadIdx.x, lane = t & 63;
  int ns = nsurvp[0];
  constexpr size_t PL = (size_t)1536 * 14336;
  int total = ns * 56;
  for (int it = blockIdx.x; it < total; it += 448) {
    int sv = it / 56, cx = it % 56;
    size_t o = (size_t)sv * 14336 + cx * 256 + t;
    float s = simsB[o] + simsB[o + PL];
    int w = surv[sv];
    int c = (s > sa[w]) ? 1 : 0;
#pragma unroll
    for (int off = 32; off > 0; off >>= 1) c += __shfl_down(c, off, 64);
    if (lane == 0 && c > 0) atomicAdd(&cnt[w], c);
  }
}

// survivor compaction: rows with partial count < 6 need the remaining columns
__global__ __launch_bounds__(256) void compact_kernel(const int* __restrict__ cnt,
                                                      int* __restrict__ surv,
                                                      int* __restrict__ nsurv) {
  __shared__ int ctr;
  if (threadIdx.x == 0) ctr = 0;
  __syncthreads();
  for (int i = threadIdx.x; i < NR2; i += 256) {
    if (cnt[i] < 6) {
      int p = atomicAdd(&ctr, 1);
      surv[p] = i;
    }
  }
  __syncthreads();
  if (threadIdx.x == 0) nsurv[0] = ctr;
}

// rowstats over summed partial logits + target-logit extraction.
// 1024 threads/block, 16 elems/thread via 2x4 float4 (sum of 2 K-planes).
__global__ __launch_bounds__(1024) void rowstats2_kernel(
    const float* __restrict__ lpart, float* __restrict__ topv,
    int* __restrict__ topi, float* __restrict__ lse,
    const int* __restrict__ targets, float* __restrict__ tl) {
  int m = blockIdx.x, t = threadIdx.x;
  const float4* A4 = (const float4*)(lpart + (size_t)m * NEMB);
  const float4* B4 = (const float4*)(lpart + (size_t)256 * NEMB + (size_t)m * NEMB);
  int tgt = targets[m];
  float v6[6]; int i6[6];
#pragma unroll
  for (int j = 0; j < 6; j++) { v6[j] = NEG_INF; i6[j] = 0x7fffffff; }
  float vals[16];
#pragma unroll
  for (int j = 0; j < 4; j++) {
    float4 f = A4[t + j * 1024];
    float4 g = B4[t + j * 1024];
    vals[j * 4 + 0] = f.x + g.x; vals[j * 4 + 1] = f.y + g.y;
    vals[j * 4 + 2] = f.z + g.z; vals[j * 4 + 3] = f.w + g.w;
  }
  float mx = vals[0];
#pragma unroll
  for (int r = 1; r < 16; r++) mx = fmaxf(mx, vals[r]);
  float sme = 0.f;
#pragma unroll
  for (int r = 0; r < 16; r++) sme += expf(vals[r] - mx);
#pragma unroll
  for (int j = 0; j < 4; j++) {
    int base = (t + j * 1024) * 4;
#pragma unroll
    for (int b = 0; b < 4; b++) {
      int idx = base + b;
      ins6i(vals[j * 4 + b], idx, v6, i6);
      if (idx == tgt) tl[m] = vals[j * 4 + b];
    }
  }
  __shared__ float sv[1024 * 6]; __shared__ int si[1024 * 6];
  __shared__ float smx[1024], ssm[1024];
#pragma unroll
  for (int j = 0; j < 6; j++) { sv[t * 6 + j] = v6[j]; si[t * 6 + j] = i6[j]; }
  smx[t] = mx; ssm[t] = sme;
  __syncthreads();
  for (int s = 512; s > 0; s >>= 1) {
    if (t < s) {
      float mo = smx[t + s], lo2 = ssm[t + s];
      float mn = fmaxf(smx[t], mo);
      ssm[t] = ssm[t] * expf(smx[t] - mn) + lo2 * expf(mo - mn);
      smx[t] = mn;
#pragma unroll
      for (int j = 0; j < 6; j++) ins6i(sv[(t + s) * 6 + j], si[(t + s) * 6 + j], v6, i6);
#pragma unroll
      for (int j = 0; j < 6; j++) { sv[t * 6 + j] = v6[j]; si[t * 6 + j] = i6[j]; }
    }
    __syncthreads();
  }
  if (t == 0) {
    lse[m] = smx[0] + logf(ssm[0]);
#pragma unroll
    for (int j = 0; j < 6; j++) { topv[m * 6 + j] = v6[j]; topi[m * 6 + j] = i6[j]; }
  }
}

// exact fp32 dot: sa[r] = em[topi[r]] . em[anchor(m=r/6)]; also zeroes cnt[r]
__global__ __launch_bounds__(256) void sa_kernel(const float* __restrict__ em,
                                                 const int* __restrict__ topi,
                                                 float* __restrict__ sa,
                                                 int* __restrict__ cnt) {
  int gid = blockIdx.x * 256 + threadIdx.x;
  int w = gid >> 6, lane = gid & 63;
  if (w >= NR2) return;
  if (lane == 1) cnt[w] = 0;
  int m = w / 6;
  int i = topi[w], a = topi[m * 6];
  const float* ei = em + (size_t)i * DIMK;
  const float* ea = em + (size_t)a * DIMK;
  float s = 0.f;
  for (int d = lane; d < DIMK; d += 64) s += ei[d] * ea[d];
#pragma unroll
  for (int off = 32; off > 0; off >>= 1) s += __shfl_down(s, off, 64);
  if (lane == 0) sa[w] = s;
}

// recip[r] == (count of sims values strictly greater than sa[r]) < 6
__global__ __launch_bounds__(256) void final_kernel(
    const float* __restrict__ tl_arr, const float* __restrict__ topv,
    const int* __restrict__ topi, const float* __restrict__ lse_arr,
    const int* __restrict__ cnt, const int* __restrict__ targets,
    float* __restrict__ out) {
  int m = threadIdx.x;
  float lse = lse_arr[m];
  int tgt = targets[m];
  float tlv = tl_arr[m];
  float beta = 0.f, Ps = 0.f, nbp = 0.f;
  bool tin = false;
#pragma unroll
  for (int k = 0; k < 6; k++) {
    int idx = topi[m * 6 + k]; float v = topv[m * 6 + k];
    float p = expf(v - lse);
    if (idx == tgt) { tin = true; beta += (lse - v); Ps += p; }
    else if (cnt[m * 6 + k] < 6) { beta += 0.5f * (lse - v); Ps += p; nbp += p; }
  }
  if (!tin) { beta += (lse - tlv); Ps += expf(tlv - lse); }
  float alpha = 9.2103404f * (1.f - Ps) + 0.6931472f * nbp;
  __shared__ float sA[256], sB2[256];
  sA[m] = alpha; sB2[m] = beta;
  __syncthreads();
  for (int s = 128; s > 0; s >>= 1) {
    if (m < s) { sA[m] += sA[m + s]; sB2[m] += sB2[m + s]; }
    __syncthreads();
  }
  if (m == 0) { out[0] = 0.05f * sA[0] / 256.f; out[1] = sB2[0] / 256.f; }
}

extern "C" void kernel_launch(void* const* d_in, const int* in_sizes, int n_in,
                              void* d_out, int out_size, void* d_ws, size_t ws_size,
                              hipStream_t stream) {
  const float* x = (const float*)d_in[0];
  const float* em = (const float*)d_in[1];
  const int* targets = (const int*)d_in[2];
  char* ws = (char*)d_ws;
  // layout (ws is 512 MB per fill-kernel WRITE_SIZE evidence; peak use ~328 MB)
  unsigned short* em_bf = (unsigned short*)ws;                 // 64 MB
  unsigned short* x_bf  = (unsigned short*)(ws + 67108864);    // 1 MB
  float* lpart  = (float*)(ws + 68157440);                     // 2 x 16 MB
  float* simsA  = (float*)(ws + 101711872);                    // 4 x 12.6 MB
  float* simsB  = (float*)(ws + 152043520);                    // 2 x 88 MB
  int*   cnt    = (int*)  (ws + 328204288);                    // 6144 B
  int*   surv   = (int*)  (ws + 328210432);                    // 6144 B
  int*   nsurv  = (int*)  (ws + 328216576);                    // 64 B
  float* topv   = (float*)(ws + 328216640);                    // 6144 B
  int*   topi   = (int*)  (ws + 328222784);                    // 6144 B
  float* lse    = (float*)(ws + 328228928);                    // 1024 B
  float* sa     = (float*)(ws + 328229952);                    // 6144 B
  float* tl     = (float*)(ws + 328236096);                    // 1024 B

  cvt_kernel<<<dim3(32768), dim3(256), 0, stream>>>(em, em_bf, NEMB * DIMK / 4);
  cvt_kernel<<<dim3(512), dim3(256), 0, stream>>>(x, x_bf, NB * DIMK / 4);
  gemm_ks<0><<<dim3(128, 4, 2), dim3(256), 0, stream>>>(
      x_bf, em_bf, (const int*)nullptr, lpart, (const int*)nullptr, (const int*)nullptr);
  rowstats2_kernel<<<dim3(256), dim3(1024), 0, stream>>>(lpart, topv, topi, lse, targets, tl);
  sa_kernel<<<dim3(384), dim3(256), 0, stream>>>(em, topi, sa, cnt);
  gemm_ks<1><<<dim3(16, 12, 4), dim3(256), 0, stream>>>(
      em_bf, em_bf, topi, simsA, (const int*)nullptr, (const int*)nullptr);
  countA_kernel<<<dim3(256), dim3(256), 0, stream>>>(simsA, sa, cnt);
  compact_kernel<<<dim3(1), dim3(256), 0, stream>>>(cnt, surv, nsurv);
  gemm_ks<2><<<dim3(112, 12, 2), dim3(256), 0, stream>>>(
      em_bf, em_bf, topi, simsB, surv, nsurv);
  countB_kernel<<<dim3(448), dim3(256), 0, stream>>>(simsB, sa, surv, nsurv, cnt);
  final_kernel<<<dim3(1), dim3(256), 0, stream>>>(tl, topv, topi, lse, cnt, targets,
                                                  (float*)d_out);
}

// Round 11
// 414.715 us; speedup vs baseline: 1.1286x; 1.1286x over previous
//
#include <hip/hip_runtime.h>
#include <math.h>

#define DIMK 2048
#define NEMB 16384
#define NB 256
#define NR2 1536          // 256*6 neighbor rows
#define INV_BETA 20.0f
#define NEG_INF (-3.0e38f)

typedef short short8 __attribute__((ext_vector_type(8)));
typedef float f32x4 __attribute__((ext_vector_type(4)));

__device__ __forceinline__ unsigned short f2bf(float f) {
  unsigned u = __float_as_uint(f);
  u += 0x7fffu + ((u >> 16) & 1u);
  return (unsigned short)(u >> 16);
}

// top-6 insert with (value desc, index asc) tie-break — matches jax top_k order
__device__ __forceinline__ void ins6i(float x, int xi, float v[6], int vi[6]) {
  if (x > v[5] || (x == v[5] && xi < vi[5])) {
    v[5] = x; vi[5] = xi;
#pragma unroll
    for (int j = 5; j > 0; j--) {
      if (v[j] > v[j - 1] || (v[j] == v[j - 1] && vi[j] < vi[j - 1])) {
        float tv = v[j]; v[j] = v[j - 1]; v[j - 1] = tv;
        int ti = vi[j]; vi[j] = vi[j - 1]; vi[j - 1] = ti;
      }
    }
  }
}

__global__ __launch_bounds__(256) void cvt_kernel(const float* __restrict__ src,
                                                  unsigned short* __restrict__ dst, int n4) {
  int i = blockIdx.x * 256 + threadIdx.x;
  if (i < n4) {
    float4 f = ((const float4*)src)[i];
    ushort4 o;
    o.x = f2bf(f.x); o.y = f2bf(f.y); o.z = f2bf(f.z); o.w = f2bf(f.w);
    ((ushort4*)dst)[i] = o;
  }
}

// ---------------- reg-staged GEMM template (R9's verified 2-deep loop) ----------------
// Wall model (10 rounds of evidence): stage wall = C0 + NK*t_iter per RESIDENT BATCH
// (768 blocks at LB(256,3)). Width free, depth costs. K-split only where the grid
// stays within one batch.
//
// MODE 0: logits = X(256xK)@em^T * 20. NKC=64, grid (128,4,1). [R9-exact]
// MODE 1: sims phase A partials — 1280 NON-ANCHOR rows (slot s -> row (s/5)*6+s%5+1;
//         k=0 rows are the anchor itself: self-sim==sa -> count 0 -> recip=1 always,
//         no compute needed). cols 0..2048, K-split z=4, NKC=16, grid (16,10,4)=640
//         blocks (one batch). out simsA[z][1280][2048].
// MODE 2: sims phase B fast — first min(ns,256) survivors, cols 2048..16384,
//         K-split z=4, NKC=16, grid (112,2,4); blocks past cap exit. partials
//         simsB[z][256][14336].
// MODE 3: sims phase B slow — survivors 256.. (normally none, blocks exit instantly),
//         full-K NKC=64, inline count epilogue. grid (112,8,1). Exactness for any ns.
template <int MODE>
__global__ __launch_bounds__(256, 3) void gemm_rs(
    const unsigned short* __restrict__ Abase, const unsigned short* __restrict__ Bbase,
    const int* __restrict__ nidx, float* __restrict__ outP,
    const float* __restrict__ saIn, int* __restrict__ cntOut,
    const int* __restrict__ surv, const int* __restrict__ nsurvp) {
  constexpr int MTILE = (MODE == 0) ? 64 : 128;
  constexpr int MI = 4;
  constexpr int NI = (MODE == 0) ? 2 : 4;
  constexpr int NSUB_A = MTILE / 16;   // 4 or 8
  constexpr int NSUB = NSUB_A + 8;     // 12 or 16
  constexpr int NA = NSUB / 4;
  constexpr int NKC = (MODE == 1 || MODE == 2) ? 16 : 64;
  constexpr int OSTRIDE = (MODE == 0) ? 16384 : ((MODE == 1) ? 2048 : 14336);
  constexpr size_t PLANE =
      (MODE == 1) ? (size_t)1280 * 2048 : ((MODE == 2) ? (size_t)256 * 14336 : 0);

  __shared__ unsigned short st[2][NSUB * 512];
  __shared__ int rowIdxSh[128];
  __shared__ float saSh[128];
  __shared__ int cntSh[128];
  __shared__ int outRowSh[128];
  int t = threadIdx.x;
  int lane = t & 63, wave = t >> 6;
  int quad = lane >> 4, l16 = lane & 15;
  int wr = (MODE == 0) ? 0 : (wave >> 1);
  int wc = (MODE == 0) ? wave : (wave & 1);
  int bn = blockIdx.x, bm = blockIdx.y, kz = blockIdx.z;
  int nvalid = 128;

  if constexpr (MODE == 1) {
    if (t < 128) {
      int slot = bm * 128 + t;
      int g = (slot / 5) * 6 + (slot % 5) + 1;   // skip k=0 (anchor-self) rows
      rowIdxSh[t] = nidx[g];
    }
    __syncthreads();
  }
  if constexpr (MODE == 2) {
    int ns = nsurvp[0];
    int nsCap = (ns < 256) ? ns : 256;
    if (bm * 128 >= nsCap) return;     // uniform, before any barrier
    if (t < 128) {
      int idx = bm * 128 + t;
      rowIdxSh[t] = nidx[surv[(idx < nsCap) ? idx : 0]];   // pad dup (ignored later)
    }
    __syncthreads();
  }
  if constexpr (MODE == 3) {
    int ns = nsurvp[0];
    if (256 + bm * 128 >= ns) return;  // normally every block exits here
    nvalid = ns - 256 - bm * 128;
    if (nvalid > 128) nvalid = 128;
    if (t < 128) {
      int idx = 256 + bm * 128 + ((t < nvalid) ? t : 0);
      int r = surv[idx];
      rowIdxSh[t] = nidx[r];
      saSh[t] = saIn[r];
      cntSh[t] = 0;
      outRowSh[t] = r;
    }
    __syncthreads();
  }

  int colbase = (MODE >= 2) ? ((bn + 16) * 128) : (bn * 128);
  int kbase = (MODE == 1 || MODE == 2) ? kz * (NKC * 32) : 0;

  const unsigned short* agp[NA];
  int soff[NA];
  {
    int seg = lane >> 4;
#pragma unroll
    for (int a = 0; a < NA; a++) {
      int s = wave + a * 4;
      size_t grow;
      const unsigned short* basep;
      if (s < NSUB_A) {
        int r = s * 16 + l16;
        grow = (MODE == 0) ? (size_t)(bm * MTILE + r) : (size_t)rowIdxSh[r];
        basep = Abase;
      } else {
        grow = (size_t)(colbase + (s - NSUB_A) * 16 + l16);
        basep = Bbase;
      }
      agp[a] = basep + grow * DIMK + kbase + seg * 8;
      soff[a] = s * 512;
    }
  }

  f32x4 acc[MI][NI];
#pragma unroll
  for (int mi = 0; mi < MI; mi++)
#pragma unroll
    for (int ni = 0; ni < NI; ni++) acc[mi][ni] = (f32x4)0.0f;

  int lo = lane * 8;

  short8 rA[NA], rB2[NA];
  auto LOADT = [&](short8* R, int kk) {
#pragma unroll
    for (int a = 0; a < NA; a++) R[a] = *(const short8*)(agp[a] + kk * 32);
  };
  auto WRITET = [&](const short8* R, int b) {
#pragma unroll
    for (int a = 0; a < NA; a++) *(short8*)&st[b][soff[a] + lo] = R[a];
  };
  auto COMPUTE = [&](int b) {
    const unsigned short* hb = &st[b][0];
    short8 af[MI], bfv[NI];
#pragma unroll
    for (int mi = 0; mi < MI; mi++)
      af[mi] = *(const short8*)&hb[(wr * MI + mi) * 512 + lo];
#pragma unroll
    for (int ni = 0; ni < NI; ni++)
      bfv[ni] = *(const short8*)&hb[(NSUB_A + wc * NI + ni) * 512 + lo];
#pragma unroll
    for (int mi = 0; mi < MI; mi++)
#pragma unroll
      for (int ni = 0; ni < NI; ni++)
        acc[mi][ni] =
            __builtin_amdgcn_mfma_f32_16x16x32_bf16(af[mi], bfv[ni], acc[mi][ni], 0, 0, 0);
  };

  LOADT(rA, 0);
  LOADT(rB2, 1);
  WRITET(rA, 0);
  __syncthreads();
  for (int k = 0; k < NKC; k += 2) {
    if (k + 2 < NKC) LOADT(rA, k + 2);
    COMPUTE(0);
    WRITET(rB2, 1);
    __syncthreads();
    if (k + 3 < NKC) LOADT(rB2, k + 3);
    COMPUTE(1);
    if (k + 2 < NKC) WRITET(rA, 0);
    __syncthreads();
  }

  if constexpr (MODE == 0) {
#pragma unroll
    for (int mi = 0; mi < MI; mi++) {
      int row = bm * MTILE + mi * 16 + quad * 4;
#pragma unroll
      for (int ni = 0; ni < NI; ni++) {
        int col = bn * 128 + wave * 32 + ni * 16 + l16;
#pragma unroll
        for (int rr = 0; rr < 4; rr++)
          outP[(size_t)(row + rr) * OSTRIDE + col] = acc[mi][ni][rr] * INV_BETA;
      }
    }
  } else if constexpr (MODE == 1 || MODE == 2) {
    float* op = outP + (size_t)kz * PLANE;
#pragma unroll
    for (int mi = 0; mi < MI; mi++) {
#pragma unroll
      for (int ni = 0; ni < NI; ni++) {
        int col = bn * 128 + wc * 64 + ni * 16 + l16;
#pragma unroll
        for (int rr = 0; rr < 4; rr++) {
          int row = bm * 128 + wr * 64 + mi * 16 + quad * 4 + rr;
          op[(size_t)row * OSTRIDE + col] = acc[mi][ni][rr];
        }
      }
    }
  } else {
    // MODE 3: inline count epilogue (R9-verified)
#pragma unroll
    for (int mi = 0; mi < MI; mi++) {
#pragma unroll
      for (int rr = 0; rr < 4; rr++) {
        int rloc = wr * 64 + mi * 16 + quad * 4 + rr;
        float s = saSh[rloc];
        int c = 0;
#pragma unroll
        for (int ni = 0; ni < NI; ni++) c += (acc[mi][ni][rr] > s) ? 1 : 0;
        c += __shfl_xor(c, 1, 64);
        c += __shfl_xor(c, 2, 64);
        c += __shfl_xor(c, 4, 64);
        c += __shfl_xor(c, 8, 64);
        if (l16 == 0) atomicAdd(&cntSh[rloc], c);
      }
    }
    __syncthreads();
    if (t < nvalid) atomicAdd(&cntOut[outRowSh[t]], cntSh[t]);
  }
}

// count phase A: cnt[g] += #(sum of 4 K-partials > sa[g]) over cols 0..2048,
// slots 0..1280 mapped to non-anchor rows g.
__global__ __launch_bounds__(256) void countA_kernel(const float* __restrict__ simsA,
                                                     const float* __restrict__ sa,
                                                     int* __restrict__ cnt) {
  int t = threadIdx.x, lane = t & 63;
  constexpr size_t PL = (size_t)1280 * 2048;
  for (int it = blockIdx.x; it < 1280 * 8; it += 256) {
    int slot = it >> 3, cx = it & 7;
    int g = (slot / 5) * 6 + (slot % 5) + 1;
    size_t o = (size_t)slot * 2048 + cx * 256 + t;
    float s = simsA[o] + simsA[o + PL] + simsA[o + 2 * PL] + simsA[o + 3 * PL];
    int c = (s > sa[g]) ? 1 : 0;
#pragma unroll
    for (int off = 32; off > 0; off >>= 1) c += __shfl_down(c, off, 64);
    if (lane == 0 && c > 0) atomicAdd(&cnt[g], c);
  }
}

// count phase B fast: first min(ns,256) survivors, cols 2048..16384 (4 K-partials)
__global__ __launch_bounds__(256) void countB_kernel(const float* __restrict__ simsB,
                                                     const float* __restrict__ sa,
                                                     const int* __restrict__ surv,
                                                     const int* __restrict__ nsurvp,
                                                     int* __restrict__ cnt) {
  int t = threadIdx.x, lane = t & 63;
  int ns = nsurvp[0];
  int nsCap = (ns < 256) ? ns : 256;
  constexpr size_t PL = (size_t)256 * 14336;
  int total = nsCap * 56;
  for (int it = blockIdx.x; it < total; it += 448) {
    int sv = it / 56, cx = it % 56;
    size_t o = (size_t)sv * 14336 + cx * 256 + t;
    float s = simsB[o] + simsB[o + PL] + simsB[o + 2 * PL] + simsB[o + 3 * PL];
    int w = surv[sv];
    int c = (s > sa[w]) ? 1 : 0;
#pragma unroll
    for (int off = 32; off > 0; off >>= 1) c += __shfl_down(c, off, 64);
    if (lane == 0 && c > 0) atomicAdd(&cnt[w], c);
  }
}

// survivor compaction: non-anchor rows (i%6 != 0) with partial count < 6.
// Anchor rows (k=0) are the anchor itself: count==0 always -> recip=1 via cnt[i]=0<6
// in final_kernel; no sims compute needed.
__global__ __launch_bounds__(256) void compact_kernel(const int* __restrict__ cnt,
                                                      int* __restrict__ surv,
                                                      int* __restrict__ nsurv) {
  __shared__ int ctr;
  if (threadIdx.x == 0) ctr = 0;
  __syncthreads();
  for (int i = threadIdx.x; i < NR2; i += 256) {
    if ((i % 6) != 0 && cnt[i] < 6) {
      int p = atomicAdd(&ctr, 1);
      surv[p] = i;
    }
  }
  __syncthreads();
  if (threadIdx.x == 0) nsurv[0] = ctr;
}

// single-pass: per-thread top6(v,i) + two-pass in-register softmax stats,
// then LDS tree merge. 1024 threads/block (16 elems/thread via 4x float4).
__global__ __launch_bounds__(1024) void rowstats_kernel(
    const float* __restrict__ logits, float* __restrict__ topv,
    int* __restrict__ topi, float* __restrict__ lse) {
  int m = blockIdx.x, t = threadIdx.x;
  const float4* row4 = (const float4*)(logits + (size_t)m * NEMB);
  float v6[6]; int i6[6];
#pragma unroll
  for (int j = 0; j < 6; j++) { v6[j] = NEG_INF; i6[j] = 0x7fffffff; }
  float vals[16];
#pragma unroll
  for (int j = 0; j < 4; j++) {
    float4 f = row4[t + j * 1024];
    vals[j * 4 + 0] = f.x; vals[j * 4 + 1] = f.y;
    vals[j * 4 + 2] = f.z; vals[j * 4 + 3] = f.w;
  }
  float mx = vals[0];
#pragma unroll
  for (int r = 1; r < 16; r++) mx = fmaxf(mx, vals[r]);
  float sme = 0.f;
#pragma unroll
  for (int r = 0; r < 16; r++) sme += expf(vals[r] - mx);
#pragma unroll
  for (int j = 0; j < 4; j++) {
    int base = (t + j * 1024) * 4;
#pragma unroll
    for (int b = 0; b < 4; b++) ins6i(vals[j * 4 + b], base + b, v6, i6);
  }
  __shared__ float sv[1024 * 6]; __shared__ int si[1024 * 6];
  __shared__ float smx[1024], ssm[1024];
#pragma unroll
  for (int j = 0; j < 6; j++) { sv[t * 6 + j] = v6[j]; si[t * 6 + j] = i6[j]; }
  smx[t] = mx; ssm[t] = sme;
  __syncthreads();
  for (int s = 512; s > 0; s >>= 1) {
    if (t < s) {
      float mo = smx[t + s], lo2 = ssm[t + s];
      float mn = fmaxf(smx[t], mo);
      ssm[t] = ssm[t] * expf(smx[t] - mn) + lo2 * expf(mo - mn);
      smx[t] = mn;
#pragma unroll
      for (int j = 0; j < 6; j++) ins6i(sv[(t + s) * 6 + j], si[(t + s) * 6 + j], v6, i6);
#pragma unroll
      for (int j = 0; j < 6; j++) { sv[t * 6 + j] = v6[j]; si[t * 6 + j] = i6[j]; }
    }
    __syncthreads();
  }
  if (t == 0) {
    lse[m] = smx[0] + logf(ssm[0]);
#pragma unroll
    for (int j = 0; j < 6; j++) { topv[m * 6 + j] = v6[j]; topi[m * 6 + j] = i6[j]; }
  }
}

// exact fp32 dot: sa[r] = em[topi[r]] . em[anchor(m=r/6)]; also zeroes cnt[r]
__global__ __launch_bounds__(256) void sa_kernel(const float* __restrict__ em,
                                                 const int* __restrict__ topi,
                                                 float* __restrict__ sa,
                                                 int* __restrict__ cnt) {
  int gid = blockIdx.x * 256 + threadIdx.x;
  int w = gid >> 6, lane = gid & 63;
  if (w >= NR2) return;
  if (lane == 1) cnt[w] = 0;
  int m = w / 6;
  int i = topi[w], a = topi[m * 6];
  const float* ei = em + (size_t)i * DIMK;
  const float* ea = em + (size_t)a * DIMK;
  float s = 0.f;
  for (int d = lane; d < DIMK; d += 64) s += ei[d] * ea[d];
#pragma unroll
  for (int off = 32; off > 0; off >>= 1) s += __shfl_down(s, off, 64);
  if (lane == 0) sa[w] = s;
}

// recip[r] == (count of sims values strictly greater than sa[r]) < 6
// (anchor rows r%6==0: cnt stays 0 -> recip=1, matching reference exactly)
__global__ __launch_bounds__(256) void final_kernel(
    const float* __restrict__ logits, const float* __restrict__ topv,
    const int* __restrict__ topi, const float* __restrict__ lse_arr,
    const int* __restrict__ cnt, const int* __restrict__ targets,
    float* __restrict__ out) {
  int m = threadIdx.x;
  float lse = lse_arr[m];
  int tgt = targets[m];
  float tl = logits[(size_t)m * NEMB + tgt];
  float beta = 0.f, Ps = 0.f, nbp = 0.f;
  bool tin = false;
#pragma unroll
  for (int k = 0; k < 6; k++) {
    int idx = topi[m * 6 + k]; float v = topv[m * 6 + k];
    float p = expf(v - lse);
    if (idx == tgt) { tin = true; beta += (lse - v); Ps += p; }
    else if (cnt[m * 6 + k] < 6) { beta += 0.5f * (lse - v); Ps += p; nbp += p; }
  }
  if (!tin) { beta += (lse - tl); Ps += expf(tl - lse); }
  float alpha = 9.2103404f * (1.f - Ps) + 0.6931472f * nbp;
  __shared__ float sA[256], sB2[256];
  sA[m] = alpha; sB2[m] = beta;
  __syncthreads();
  for (int s = 128; s > 0; s >>= 1) {
    if (m < s) { sA[m] += sA[m + s]; sB2[m] += sB2[m + s]; }
    __syncthreads();
  }
  if (m == 0) { out[0] = 0.05f * sA[0] / 256.f; out[1] = sB2[0] / 256.f; }
}

extern "C" void kernel_launch(void* const* d_in, const int* in_sizes, int n_in,
                              void* d_out, int out_size, void* d_ws, size_t ws_size,
                              hipStream_t stream) {
  const float* x = (const float*)d_in[0];
  const float* em = (const float*)d_in[1];
  const int* targets = (const int*)d_in[2];
  char* ws = (char*)d_ws;
  unsigned short* em_bf = (unsigned short*)ws;                 // 64 MB
  unsigned short* x_bf  = (unsigned short*)(ws + 67108864);    // 1 MB
  float* logits = (float*)(ws + 68157440);                     // 16 MB
  float* simsA  = (float*)(ws + 84934656);                     // 4 x 10 MB
  float* simsB  = (float*)(ws + 126877696);                    // 4 x 14 MB
  int*   cnt    = (int*)  (ws + 185597952);                    // 6144 B
  int*   surv   = (int*)  (ws + 185604096);                    // 6144 B
  int*   nsurv  = (int*)  (ws + 185610240);                    // 64 B
  float* topv   = (float*)(ws + 185610304);                    // 6144 B
  int*   topi   = (int*)  (ws + 185616448);                    // 6144 B
  float* lse    = (float*)(ws + 185622592);                    // 1024 B
  float* sa     = (float*)(ws + 185623616);                    // 6144 B

  cvt_kernel<<<dim3(32768), dim3(256), 0, stream>>>(em, em_bf, NEMB * DIMK / 4);
  cvt_kernel<<<dim3(512), dim3(256), 0, stream>>>(x, x_bf, NB * DIMK / 4);
  gemm_rs<0><<<dim3(128, 4, 1), dim3(256), 0, stream>>>(
      x_bf, em_bf, (const int*)nullptr, logits, (const float*)nullptr, (int*)nullptr,
      (const int*)nullptr, (const int*)nullptr);
  rowstats_kernel<<<dim3(256), dim3(1024), 0, stream>>>(logits, topv, topi, lse);
  sa_kernel<<<dim3(384), dim3(256), 0, stream>>>(em, topi, sa, cnt);
  gemm_rs<1><<<dim3(16, 10, 4), dim3(256), 0, stream>>>(
      em_bf, em_bf, topi, simsA, (const float*)nullptr, (int*)nullptr,
      (const int*)nullptr, (const int*)nullptr);
  countA_kernel<<<dim3(256), dim3(256), 0, stream>>>(simsA, sa, cnt);
  compact_kernel<<<dim3(1), dim3(256), 0, stream>>>(cnt, surv, nsurv);
  gemm_rs<2><<<dim3(112, 2, 4), dim3(256), 0, stream>>>(
      em_bf, em_bf, topi, simsB, (const float*)nullptr, (int*)nullptr, surv, nsurv);
  countB_kernel<<<dim3(448), dim3(256), 0, stream>>>(simsB, sa, surv, nsurv, cnt);
  gemm_rs<3><<<dim3(112, 8, 1), dim3(256), 0, stream>>>(
      em_bf, em_bf, topi, (float*)nullptr, sa, cnt, surv, nsurv);
  final_kernel<<<dim3(1), dim3(256), 0, stream>>>(logits, topv, topi, lse, cnt, targets,
                                                  (float*)d_out);
}